// Round 4
// baseline (475.990 us; speedup 1.0000x reference)
//
#include <hip/hip_runtime.h>
#include <hip/hip_bf16.h>
#include <cstdint>
#include <cstddef>

// Problem constants: X[S,B,D], W[3H,D], S=2048 B=16 D=1024 H=1024
#define S_LEN 2048
#define BATCH 16
#define DIM   1024
#define HID   1024
#define M_TOT (S_LEN * BATCH)   // 32768
#define N_TOT (3 * HID)         // 3072
#define K_TOT DIM               // 1024
#define NCHUNK 32
#define CHLEN (S_LEN / NCHUNK)  // 64

// GEMM geometry: 256x256 tile, BK=32, 8 waves (2M x 4N), 32x32x16 MFMA
#define BM 256
#define BN 256
#define BK 32
#define NT (K_TOT / BK)          // 32 K-tiles
#define GRID_M (M_TOT / BM)      // 128
#define GRID_N (N_TOT / BN)      // 12
#define NWG (GRID_M * GRID_N)    // 1536 (divisible by 8)

typedef __bf16 bf16x8 __attribute__((ext_vector_type(8)));
typedef float  f32x16 __attribute__((ext_vector_type(16)));

__device__ __forceinline__ unsigned short f2bf(float f) {
    unsigned int u = __float_as_uint(f);
    u += 0x7FFFu + ((u >> 16) & 1u);   // RNE
    return (unsigned short)(u >> 16);
}
__device__ __forceinline__ float bf2f(unsigned int s) {
    return __uint_as_float(s << 16);
}
__device__ __forceinline__ float fast_sigmoid(float x) { return 1.0f / (1.0f + __expf(-x)); }
__device__ __forceinline__ float fast_tanh(float x)    { return 2.0f / (1.0f + __expf(-2.0f * x)) - 1.0f; }

// ---------------- fp32 -> bf16 conversion (X and W) ----------------
__global__ void __launch_bounds__(256) cvt_f32_bf16(const float* __restrict__ in,
                                                    unsigned short* __restrict__ out, int n4) {
    int i = blockIdx.x * blockDim.x + threadIdx.x;
    const int stride = gridDim.x * blockDim.x;
    for (; i < n4; i += stride) {
        const float4 v = reinterpret_cast<const float4*>(in)[i];
        ushort4 o;
        o.x = f2bf(v.x); o.y = f2bf(v.y); o.z = f2bf(v.z); o.w = f2bf(v.w);
        reinterpret_cast<ushort4*>(out)[i] = o;
    }
}

// ---------------- GEMM: gates = act(X * W^T + b), bf16 out ----------------
// Round-2 proven skeleton (BK=32, 4-slot ring, FULL-TILE vmcnt guarantees)
// + 4-phase per-tile interleave (T3) + 32x32x16 MFMA (coalesced 64B C-writes).
// LDS XOR-swizzle (granule ^= (row>>1)&3 per 64B row) staged via pre-swizzled
// global source; all fragment reads of tile t touch only slot t&3 (fully staged).
#define GLOAD_LDS16(gp, lp)                                                         \
    __builtin_amdgcn_global_load_lds((__attribute__((address_space(1))) void*)(gp), \
                                     (__attribute__((address_space(3))) void*)(lp), 16, 0, 0)

__global__ void __launch_bounds__(512, 2)
gemm_gates(const unsigned short* __restrict__ Xb,
           const unsigned short* __restrict__ Wb,
           const float* __restrict__ bias,
           unsigned short* __restrict__ gates) {
    __shared__ unsigned short As[4][BM * BK];   // 4 x 16 KiB
    __shared__ unsigned short Bs[4][BN * BK];   // 4 x 16 KiB  (128 KiB total)

    const int tid  = threadIdx.x;
    const int lane = tid & 63;
    const int wid  = tid >> 6;     // 0..7
    const int wm   = wid >> 2;     // 0..1  (wave output 128x64 at (wm*128, wn*64))
    const int wn   = wid & 3;      // 0..3
    const int l31  = lane & 31;
    const int lhi  = lane >> 5;    // 0..1

    // XCD-aware bijective swizzle; bn-fastest -> A-panels L2-resident per XCD
    const int swz = (blockIdx.x & 7) * (NWG / 8) + (blockIdx.x >> 3);
    const int bn = swz % GRID_N;
    const int bm = swz / GRID_N;

    // Staging (round-2 verified): one issue = 512 thr x 16B = 128 rows x 64B.
    // Thread (r = tid>>2, p = tid&3) writes physical granule p of row r; the
    // global source column is pre-swizzled: logical granule g = p ^ ((r>>1)&3).
    // Row offsets are multiples of 128 -> (r>>1)&3 invariant across issues.
    const int srow  = tid >> 2;                                  // 0..127
    const int scolE = (((tid & 3) ^ ((tid >> 3) & 3)) << 3);     // pre-swizzled col
    const unsigned short* gA = Xb + (size_t)(bm * BM + srow) * K_TOT + scolE;
    const unsigned short* gB = Wb + (size_t)(bn * BN + srow) * K_TOT + scolE;
    unsigned short* lA = &As[0][tid * 8];   // tid*16 bytes, linear dest
    unsigned short* lB = &Bs[0][tid * 8];

    // One GLOAD issue; i = 0,1: A rows 0-127 / 128-255; i = 2,3: B likewise.
#define STAGE_I(tt, i) do { const int _s = (tt) & 3;                                             \
        if ((i) < 2) GLOAD_LDS16(gA + (size_t)(i) * 128 * K_TOT + (tt) * BK,                     \
                                 lA + _s * (BM * BK) + (i) * 4096);                              \
        else         GLOAD_LDS16(gB + (size_t)((i) - 2) * 128 * K_TOT + (tt) * BK,               \
                                 lB + _s * (BN * BK) + ((i) - 2) * 4096);                        \
    } while (0)

    // Fragment reads (32x32x16): lane (l31,lhi) reads row r, k-granule kk*2+lhi
    // (8 contiguous bf16 = 16B), physically at granule ^ ((r>>1)&3). The same
    // k-mapping on A and B makes any HW k-permutation dot-product-invariant.
#define LDA_F(dst, s, m, kk) do {                                               \
        const int _r  = wm * 128 + (m) * 32 + l31;                              \
        const int _pg = ((kk) * 2 + lhi) ^ ((_r >> 1) & 3);                     \
        dst = *reinterpret_cast<const bf16x8*>(&As[s][_r * BK + _pg * 8]); } while (0)
#define LDB_F(dst, s, n, kk) do {                                               \
        const int _r  = wn * 64 + (n) * 32 + l31;                               \
        const int _pg = ((kk) * 2 + lhi) ^ ((_r >> 1) & 3);                     \
        dst = *reinterpret_cast<const bf16x8*>(&Bs[s][_r * BK + _pg * 8]); } while (0)

    f32x16 acc[4][2];
#pragma unroll
    for (int m = 0; m < 4; ++m)
#pragma unroll
        for (int n = 0; n < 2; ++n)
#pragma unroll
            for (int r = 0; r < 16; ++r) acc[m][n][r] = 0.0f;

    bf16x8 a[4][2], b[2][2];

    // Prologue: stage tiles 0,1,2 fully (12 loads); vmcnt(8) -> tile 0 resident
    STAGE_I(0, 0); STAGE_I(0, 1); STAGE_I(0, 2); STAGE_I(0, 3);
    STAGE_I(1, 0); STAGE_I(1, 1); STAGE_I(1, 2); STAGE_I(1, 3);
    STAGE_I(2, 0); STAGE_I(2, 1); STAGE_I(2, 2); STAGE_I(2, 3);
    asm volatile("s_waitcnt vmcnt(8)" ::: "memory");
    __builtin_amdgcn_s_barrier();

#pragma unroll 1
    for (int t = 0; t < NT; ++t) {
        const int s = t & 3;
        // ---- phase 0: read a[0],a[1],b[0] (6 ds_read); stage issue 0; MFMA m01 x n0 ----
#pragma unroll
        for (int mi = 0; mi < 2; ++mi)
#pragma unroll
            for (int kk = 0; kk < 2; ++kk) LDA_F(a[mi][kk], s, mi, kk);
#pragma unroll
        for (int kk = 0; kk < 2; ++kk) LDB_F(b[0][kk], s, 0, kk);
        if (t + 3 < NT) STAGE_I(t + 3, 0);
        __builtin_amdgcn_s_barrier();
        __builtin_amdgcn_s_setprio(1);
#pragma unroll
        for (int mi = 0; mi < 2; ++mi)
#pragma unroll
            for (int kk = 0; kk < 2; ++kk)
                acc[mi][0] = __builtin_amdgcn_mfma_f32_32x32x16_bf16(a[mi][kk], b[0][kk], acc[mi][0], 0, 0, 0);
        __builtin_amdgcn_s_setprio(0);
        __builtin_amdgcn_s_barrier();
        // ---- phase 1: read a[2],a[3] (4 ds_read); stage issue 1; MFMA m23 x n0 ----
#pragma unroll
        for (int mi = 0; mi < 2; ++mi)
#pragma unroll
            for (int kk = 0; kk < 2; ++kk) LDA_F(a[2 + mi][kk], s, 2 + mi, kk);
        if (t + 3 < NT) STAGE_I(t + 3, 1);
        __builtin_amdgcn_s_barrier();
        __builtin_amdgcn_s_setprio(1);
#pragma unroll
        for (int mi = 0; mi < 2; ++mi)
#pragma unroll
            for (int kk = 0; kk < 2; ++kk)
                acc[2 + mi][0] = __builtin_amdgcn_mfma_f32_32x32x16_bf16(a[2 + mi][kk], b[0][kk], acc[2 + mi][0], 0, 0, 0);
        __builtin_amdgcn_s_setprio(0);
        __builtin_amdgcn_s_barrier();
        // ---- phase 2: read b[1] (2 ds_read); stage issue 2; MFMA m01 x n1 ----
#pragma unroll
        for (int kk = 0; kk < 2; ++kk) LDB_F(b[1][kk], s, 1, kk);
        if (t + 3 < NT) STAGE_I(t + 3, 2);
        __builtin_amdgcn_s_barrier();
        __builtin_amdgcn_s_setprio(1);
#pragma unroll
        for (int mi = 0; mi < 2; ++mi)
#pragma unroll
            for (int kk = 0; kk < 2; ++kk)
                acc[mi][1] = __builtin_amdgcn_mfma_f32_32x32x16_bf16(a[mi][kk], b[1][kk], acc[mi][1], 0, 0, 0);
        __builtin_amdgcn_s_setprio(0);
        __builtin_amdgcn_s_barrier();
        // ---- phase 3: stage issue 3; counted vmcnt (tile t+1 resident); MFMA m23 x n1 ----
        if (t + 3 < NT) {
            STAGE_I(t + 3, 3);
            asm volatile("s_waitcnt vmcnt(8)" ::: "memory");   // oldest 4 = tile t+1
        } else if (t + 3 == NT) {
            asm volatile("s_waitcnt vmcnt(4)" ::: "memory");
        } else if (t + 2 == NT) {
            asm volatile("s_waitcnt vmcnt(0)" ::: "memory");
        }
        __builtin_amdgcn_s_barrier();
        __builtin_amdgcn_s_setprio(1);
#pragma unroll
        for (int mi = 0; mi < 2; ++mi)
#pragma unroll
            for (int kk = 0; kk < 2; ++kk)
                acc[2 + mi][1] = __builtin_amdgcn_mfma_f32_32x32x16_bf16(a[2 + mi][kk], b[1][kk], acc[2 + mi][1], 0, 0, 0);
        __builtin_amdgcn_s_setprio(0);
        __builtin_amdgcn_s_barrier();
    }
#undef STAGE_I
#undef LDA_F
#undef LDB_F

    // Epilogue: bias + activation, bf16 store.
    // 32x32 C/D: col = lane&31, row = (reg&3) + 8*(reg>>2) + 4*(lane>>5)  [m74/m101]
    // Each store: 32 lanes x 2B = 64B contiguous, 64B-aligned = full HBM sector.
    const int gate_id = bn >> 2;  // 0:tanh(Z) 1:sig(F) 2:sig(O), uniform per block
#pragma unroll
    for (int n = 0; n < 2; ++n) {
        const int col = bn * BN + wn * 64 + n * 32 + l31;
        const float bb = bias[col];
#pragma unroll
        for (int m = 0; m < 4; ++m) {
            const int rb = bm * BM + wm * 128 + m * 32 + 4 * lhi;
#pragma unroll
            for (int r = 0; r < 16; ++r) {
                const int row = rb + (r & 3) + 8 * (r >> 2);
                const float y = acc[m][n][r] + bb;
                const float g = (gate_id == 0) ? fast_tanh(y) : fast_sigmoid(y);
                gates[(size_t)row * N_TOT + col] = f2bf(g);
            }
        }
    }
}

// ---------------- chunked linear scan (fo-pool), vec2 over h ----------------
__global__ void __launch_bounds__(256) scan_phase1(const unsigned short* __restrict__ gates,
                                                   float* __restrict__ Aprod,
                                                   float* __restrict__ Cend) {
    const int t = blockIdx.x * 256 + threadIdx.x;  // chunk*8192 + b*512 + hp
    const int hp = t & 511;
    const int b  = (t >> 9) & (BATCH - 1);
    const int chunk = t >> 13;
    float c0 = 0.f, c1 = 0.f, a0 = 1.f, a1 = 1.f;
    const int m0 = chunk * (CHLEN * BATCH) + b;
    const unsigned short* gz = gates + (size_t)m0 * N_TOT + hp * 2;
#pragma unroll 4
    for (int i = 0; i < CHLEN; ++i) {
        const unsigned short* p = gz + (size_t)i * BATCH * N_TOT;
        const unsigned int zz = *reinterpret_cast<const unsigned int*>(p);
        const unsigned int ff = *reinterpret_cast<const unsigned int*>(p + HID);
        const float z0 = bf2f(zz & 0xffffu), z1 = bf2f(zz >> 16);
        const float f0 = bf2f(ff & 0xffffu), f1 = bf2f(ff >> 16);
        const float o0 = 1.f - f0, o1 = 1.f - f1;
        c0 = f0 * z0 + o0 * c0;  c1 = f1 * z1 + o1 * c1;
        a0 *= o0;                a1 *= o1;
    }
    const int idx = chunk * (BATCH * HID) + b * HID + hp * 2;
    *reinterpret_cast<float2*>(&Aprod[idx]) = make_float2(a0, a1);
    *reinterpret_cast<float2*>(&Cend[idx])  = make_float2(c0, c1);
}

__global__ void __launch_bounds__(256) scan_combine(const float* __restrict__ Aprod,
                                                    const float* __restrict__ Cend,
                                                    const float* __restrict__ hidden,
                                                    float* __restrict__ Cstart,
                                                    float* __restrict__ c_last) {
    const int t = blockIdx.x * 256 + threadIdx.x;  // b*1024 + h
    float c = hidden[t];
#pragma unroll
    for (int j = 0; j < NCHUNK; ++j) {
        const int idx = j * (BATCH * HID) + t;
        Cstart[idx] = c;
        c = Aprod[idx] * c + Cend[idx];
    }
    c_last[t] = c;
}

__global__ void __launch_bounds__(256) scan_phase3(const unsigned short* __restrict__ gates,
                                                   const float* __restrict__ Cstart,
                                                   float* __restrict__ Hout) {
    const int t = blockIdx.x * 256 + threadIdx.x;
    const int hp = t & 511;
    const int b  = (t >> 9) & (BATCH - 1);
    const int chunk = t >> 13;
    const int idx = chunk * (BATCH * HID) + b * HID + hp * 2;
    float2 cs = *reinterpret_cast<const float2*>(&Cstart[idx]);
    float c0 = cs.x, c1 = cs.y;
    const int m0 = chunk * (CHLEN * BATCH) + b;
    const unsigned short* gz = gates + (size_t)m0 * N_TOT + hp * 2;
#pragma unroll 4
    for (int i = 0; i < CHLEN; ++i) {
        const unsigned short* p = gz + (size_t)i * BATCH * N_TOT;
        const unsigned int zz = *reinterpret_cast<const unsigned int*>(p);
        const unsigned int ff = *reinterpret_cast<const unsigned int*>(p + HID);
        const unsigned int oo = *reinterpret_cast<const unsigned int*>(p + 2 * HID);
        const float z0 = bf2f(zz & 0xffffu), z1 = bf2f(zz >> 16);
        const float f0 = bf2f(ff & 0xffffu), f1 = bf2f(ff >> 16);
        const float g0 = bf2f(oo & 0xffffu), g1 = bf2f(oo >> 16);
        c0 = f0 * z0 + (1.f - f0) * c0;
        c1 = f1 * z1 + (1.f - f1) * c1;
        const int m = m0 + i * BATCH;
        *reinterpret_cast<float2*>(&Hout[(size_t)m * HID + hp * 2]) = make_float2(g0 * c0, g1 * c1);
    }
}

// ---------------- launch ----------------
extern "C" void kernel_launch(void* const* d_in, const int* in_sizes, int n_in,
                              void* d_out, int out_size, void* d_ws, size_t ws_size,
                              hipStream_t stream) {
    const float* X      = (const float*)d_in[0];
    const float* hidden = (const float*)d_in[1];
    const float* W      = (const float*)d_in[2];
    const float* bias   = (const float*)d_in[3];
    float* out    = (float*)d_out;
    float* c_last = out + (size_t)M_TOT * HID;   // outputs: H_out then C[-1:]

    char* ws = (char*)d_ws;
    unsigned short* Xb    = (unsigned short*)ws;                                // 64 MiB
    unsigned short* Wb    = (unsigned short*)(ws + (size_t)M_TOT * K_TOT * 2);  // 6 MiB
    unsigned short* gates = Wb + (size_t)N_TOT * K_TOT;                         // 192 MiB bf16
    float* Aprod  = (float*)(gates + (size_t)M_TOT * N_TOT);
    float* Cend   = Aprod + (size_t)NCHUNK * BATCH * HID;
    float* Cstart = Cend  + (size_t)NCHUNK * BATCH * HID;

    cvt_f32_bf16<<<dim3(2048), dim3(256), 0, stream>>>(X, Xb, (int)(M_TOT * K_TOT / 4));
    cvt_f32_bf16<<<dim3(512),  dim3(256), 0, stream>>>(W, Wb, (int)(N_TOT * K_TOT / 4));
    gemm_gates<<<dim3(NWG), dim3(512), 0, stream>>>(Xb, Wb, bias, gates);
    scan_phase1<<<dim3(1024), dim3(256), 0, stream>>>(gates, Aprod, Cend);
    scan_combine<<<dim3(64), dim3(256), 0, stream>>>(Aprod, Cend, hidden, Cstart, c_last);
    scan_phase3<<<dim3(1024), dim3(256), 0, stream>>>(gates, Cstart, out);
}

// Round 5
// 422.618 us; speedup vs baseline: 1.1263x; 1.1263x over previous
//
#include <hip/hip_runtime.h>
#include <hip/hip_bf16.h>
#include <cstdint>
#include <cstddef>

// Problem constants: X[S,B,D], W[3H,D], S=2048 B=16 D=1024 H=1024
#define S_LEN 2048
#define BATCH 16
#define DIM   1024
#define HID   1024
#define M_TOT (S_LEN * BATCH)   // 32768
#define N_TOT (3 * HID)         // 3072
#define K_TOT DIM               // 1024
#define NCHUNK 32
#define CHLEN (S_LEN / NCHUNK)  // 64

// GEMM geometry: 256x256 tile, BK=64, 8 waves (2M x 4N), 16x16x32 MFMA, 8-phase
#define BM 256
#define BN 256
#define BK 64
#define NT (K_TOT / BK)          // 16 K-tiles
#define NITER (NT / 2)           // 8 iters, 2 K-tiles each
#define GRID_M (M_TOT / BM)      // 128
#define GRID_N (N_TOT / BN)      // 12
#define NWG (GRID_M * GRID_N)    // 1536 (divisible by 8)

typedef __bf16 bf16x8 __attribute__((ext_vector_type(8)));
typedef float  f32x4  __attribute__((ext_vector_type(4)));

__device__ __forceinline__ unsigned short f2bf(float f) {
    unsigned int u = __float_as_uint(f);
    u += 0x7FFFu + ((u >> 16) & 1u);   // RNE
    return (unsigned short)(u >> 16);
}
__device__ __forceinline__ float bf2f(unsigned int s) {
    return __uint_as_float(s << 16);
}
__device__ __forceinline__ float fast_sigmoid(float x) { return 1.0f / (1.0f + __expf(-x)); }
__device__ __forceinline__ float fast_tanh(float x)    { return 2.0f / (1.0f + __expf(-2.0f * x)) - 1.0f; }

// ---------------- fp32 -> bf16 conversion (X and W) ----------------
__global__ void __launch_bounds__(256) cvt_f32_bf16(const float* __restrict__ in,
                                                    unsigned short* __restrict__ out, int n4) {
    int i = blockIdx.x * blockDim.x + threadIdx.x;
    const int stride = gridDim.x * blockDim.x;
    for (; i < n4; i += stride) {
        const float4 v = reinterpret_cast<const float4*>(in)[i];
        ushort4 o;
        o.x = f2bf(v.x); o.y = f2bf(v.y); o.z = f2bf(v.z); o.w = f2bf(v.w);
        reinterpret_cast<ushort4*>(out)[i] = o;
    }
}

// ---------------- GEMM: gates = act(X * W^T + b), bf16 out ----------------
// m201-style 8-phase schedule: 2 K-tiles/iter, per phase {ds_read subtile |
// stage 2 quarter-tiles | barrier | setprio+16 MFMA | [vmcnt(6) at ph4/ph8] |
// barrier}. LDS rows are 128B: G4-proven XOR swizzle slot ^= (row&7), staged
// via pre-swizzled global column (global_load_lds writes linearly).
#define GLOAD_LDS16(gp, lp)                                                         \
    __builtin_amdgcn_global_load_lds((__attribute__((address_space(1))) void*)(gp), \
                                     (__attribute__((address_space(3))) void*)(lp), 16, 0, 0)

__global__ void __launch_bounds__(512, 2)
gemm_gates(const unsigned short* __restrict__ Xb,
           const unsigned short* __restrict__ Wb,
           const float* __restrict__ bias,
           unsigned short* __restrict__ gates) {
    __shared__ unsigned short As[2][BM * BK];   // 2 x 32 KiB
    __shared__ unsigned short Bs[2][BN * BK];   // 2 x 32 KiB  (128 KiB)

    const int tid  = threadIdx.x;
    const int lane = tid & 63;
    const int wid  = tid >> 6;     // 0..7
    const int wm   = wid >> 2;     // 0..1  (wave out 128x64 at (wm*128, wn*64))
    const int wn   = wid & 3;      // 0..3
    const int lr   = lane & 15;
    const int lc   = (lane >> 4) & 3;

    // XCD-aware bijective swizzle; bn-fastest -> A-panels L2-resident per XCD
    const int swz = (blockIdx.x & 7) * (NWG / 8) + (blockIdx.x >> 3);
    const int bn = swz % GRID_N;
    const int bm = swz / GRID_N;

    // Staging: one issue = 512 thr x 16B = 64 rows x 128B (one quarter-tile).
    // Thread t writes physical 16B-slot p=t&7 of local row rl=t>>3; logical
    // slot g = p ^ (rl&7)  =>  pre-swizzled global column.
    const int srow  = tid >> 3;                                  // 0..63
    const int scolE = (((tid & 7) ^ ((tid >> 3) & 7)) << 3);     // pre-swizzled col
    const unsigned short* gAs = Xb + (size_t)(bm * BM + srow) * K_TOT + scolE;
    const unsigned short* gBs = Wb + (size_t)(bn * BN + srow) * K_TOT + scolE;

#define STAGE_A(T, q) GLOAD_LDS16(gAs + (size_t)(q) * 64 * K_TOT + (T) * BK, \
                                  &As[(T) & 1][(q) * 4096 + tid * 8])
#define STAGE_B(T, q) GLOAD_LDS16(gBs + (size_t)(q) * 64 * K_TOT + (T) * BK, \
                                  &Bs[(T) & 1][(q) * 4096 + tid * 8])

    // Fragment reads (16x16x32, round-2 proven mapping): row = base+lr,
    // k-elems = kw*32 + lc*8 + 0..7; physical slot = (kw*4+lc) ^ (row&7).
#define LDA(dst, s, mf, kw) do { const int _r = wm * 128 + (mf) * 16 + lr;            \
        dst = *reinterpret_cast<const bf16x8*>(                                        \
            &As[s][_r * 64 + (((((kw) << 2) | lc) ^ (_r & 7)) << 3)]); } while (0)
#define LDB(dst, s, nf, kw) do { const int _r = wn * 64 + (nf) * 16 + lr;             \
        dst = *reinterpret_cast<const bf16x8*>(                                        \
            &Bs[s][_r * 64 + (((((kw) << 2) | lc) ^ (_r & 7)) << 3)]); } while (0)

#define RD_A(s, MH) do { _Pragma("unroll") for (int mi = 0; mi < 4; ++mi) {           \
        LDA(a[mi][0], s, (MH) * 4 + mi, 0); LDA(a[mi][1], s, (MH) * 4 + mi, 1); } } while (0)
#define RD_B(dst, s, NH) do { _Pragma("unroll") for (int ni = 0; ni < 2; ++ni) {      \
        LDB(dst[ni][0], s, (NH) * 2 + ni, 0); LDB(dst[ni][1], s, (NH) * 2 + ni, 1); } } while (0)

#define MM16(A_, B_, M0, N0) do {                                                     \
    _Pragma("unroll") for (int mi = 0; mi < 4; ++mi)                                  \
    _Pragma("unroll") for (int ni = 0; ni < 2; ++ni) {                                \
        acc[(M0) + mi][(N0) + ni] = __builtin_amdgcn_mfma_f32_16x16x32_bf16(          \
            A_[mi][0], B_[ni][0], acc[(M0) + mi][(N0) + ni], 0, 0, 0);                \
        acc[(M0) + mi][(N0) + ni] = __builtin_amdgcn_mfma_f32_16x16x32_bf16(          \
            A_[mi][1], B_[ni][1], acc[(M0) + mi][(N0) + ni], 0, 0, 0);                \
    } } while (0)

#define BAR __builtin_amdgcn_s_barrier()
#define SP1 __builtin_amdgcn_s_setprio(1)
#define SP0 __builtin_amdgcn_s_setprio(0)

    f32x4 acc[8][4];
#pragma unroll
    for (int m = 0; m < 8; ++m)
#pragma unroll
        for (int n = 0; n < 4; ++n) acc[m][n] = {0.0f, 0.0f, 0.0f, 0.0f};

    bf16x8 a[4][2], b[2][2], b2[2][2];

    // Prologue: tile 0 fully (8), tile 1 partially (6, ordered as steady state)
    STAGE_A(0, 0); STAGE_A(0, 1); STAGE_A(0, 2); STAGE_A(0, 3);
    STAGE_B(0, 0); STAGE_B(0, 1); STAGE_B(0, 2); STAGE_B(0, 3);
    STAGE_A(1, 0); STAGE_A(1, 2);
    STAGE_B(1, 0); STAGE_B(1, 1);
    STAGE_A(1, 1); STAGE_A(1, 3);
    asm volatile("s_waitcnt vmcnt(6)" ::: "memory");   // tile 0 resident
    BAR;

#pragma unroll 1
    for (int j = 0; j < NITER; ++j) {
        const int t0 = 2 * j;          // slot 0
        const int t1 = 2 * j + 1;      // slot 1
        const bool st = (j < NITER - 1);
        // ---- ph1: read A-mh0 + B-nh0 (12); stage B(t1)[q2,q3]; MFMA (0,0) ----
        RD_A(0, 0); RD_B(b, 0, 0);
        STAGE_B(t1, 2); STAGE_B(t1, 3);
        BAR; SP1; MM16(a, b, 0, 0); SP0; BAR;
        // ---- ph2: read B-nh1 (4); stage A(t0+2)[q0,q2]; MFMA (0,1) ----
        RD_B(b2, 0, 1);
        if (st) { STAGE_A(t0 + 2, 0); STAGE_A(t0 + 2, 2); }
        BAR; SP1; MM16(a, b2, 0, 2); SP0; BAR;
        // ---- ph3: read A-mh1 (8); stage B(t0+2)[q0,q1]; MFMA (1,0) ----
        RD_A(0, 1);
        if (st) { STAGE_B(t0 + 2, 0); STAGE_B(t0 + 2, 1); }
        BAR; SP1; MM16(a, b, 4, 0); SP0; BAR;
        // ---- ph4: stage A(t0+2)[q1,q3]; MFMA (1,1); vmcnt -> tile t1 resident ----
        if (st) { STAGE_A(t0 + 2, 1); STAGE_A(t0 + 2, 3); }
        BAR; SP1; MM16(a, b2, 4, 2); SP0;
        if (st) asm volatile("s_waitcnt vmcnt(6)" ::: "memory");
        else    asm volatile("s_waitcnt vmcnt(0)" ::: "memory");
        BAR;
        // ---- ph5: read A-mh0 + B-nh0 of t1 (12); stage B(t0+2)[q2,q3]; MFMA (0,0) ----
        RD_A(1, 0); RD_B(b, 1, 0);
        if (st) { STAGE_B(t0 + 2, 2); STAGE_B(t0 + 2, 3); }
        BAR; SP1; MM16(a, b, 0, 0); SP0; BAR;
        // ---- ph6: read B-nh1 (4); stage A(t1+2)[q0,q2]; MFMA (0,1) ----
        RD_B(b2, 1, 1);
        if (st) { STAGE_A(t1 + 2, 0); STAGE_A(t1 + 2, 2); }
        BAR; SP1; MM16(a, b2, 0, 2); SP0; BAR;
        // ---- ph7: read A-mh1 (8); stage B(t1+2)[q0,q1]; MFMA (1,0) ----
        RD_A(1, 1);
        if (st) { STAGE_B(t1 + 2, 0); STAGE_B(t1 + 2, 1); }
        BAR; SP1; MM16(a, b, 4, 0); SP0; BAR;
        // ---- ph8: stage A(t1+2)[q1,q3]; MFMA (1,1); vmcnt -> tile t0+2 resident ----
        if (st) { STAGE_A(t1 + 2, 1); STAGE_A(t1 + 2, 3); }
        BAR; SP1; MM16(a, b2, 4, 2); SP0;
        if (st) asm volatile("s_waitcnt vmcnt(6)" ::: "memory");
        BAR;
    }
#undef STAGE_A
#undef STAGE_B
#undef LDA
#undef LDB
#undef RD_A
#undef RD_B
#undef MM16
#undef BAR
#undef SP1
#undef SP0

    // Epilogue: bias + activation, bf16 store (round-2 proven 16x16 C/D layout:
    // col = lane&15, row = (lane>>4)*4 + reg).
    const int gate_id = bn >> 2;  // 0:tanh(Z) 1:sig(F) 2:sig(O), uniform per block
    const int c0 = bn * BN + wn * 64 + lr;
    const int r0 = bm * BM + wm * 128 + ((lane >> 4) << 2);
#pragma unroll
    for (int nf = 0; nf < 4; ++nf) {
        const int col = c0 + nf * 16;
        const float bb = bias[col];
#pragma unroll
        for (int mf = 0; mf < 8; ++mf) {
            const int rowb = r0 + mf * 16;
#pragma unroll
            for (int r = 0; r < 4; ++r) {
                const float y = acc[mf][nf][r] + bb;
                const float g = (gate_id == 0) ? fast_tanh(y) : fast_sigmoid(y);
                gates[(size_t)(rowb + r) * N_TOT + col] = f2bf(g);
            }
        }
    }
}

// ---------------- chunked linear scan (fo-pool), vec2 over h ----------------
__global__ void __launch_bounds__(256) scan_phase1(const unsigned short* __restrict__ gates,
                                                   float* __restrict__ Aprod,
                                                   float* __restrict__ Cend) {
    const int t = blockIdx.x * 256 + threadIdx.x;  // chunk*8192 + b*512 + hp
    const int hp = t & 511;
    const int b  = (t >> 9) & (BATCH - 1);
    const int chunk = t >> 13;
    float c0 = 0.f, c1 = 0.f, a0 = 1.f, a1 = 1.f;
    const int m0 = chunk * (CHLEN * BATCH) + b;
    const unsigned short* gz = gates + (size_t)m0 * N_TOT + hp * 2;
#pragma unroll 4
    for (int i = 0; i < CHLEN; ++i) {
        const unsigned short* p = gz + (size_t)i * BATCH * N_TOT;
        const unsigned int zz = *reinterpret_cast<const unsigned int*>(p);
        const unsigned int ff = *reinterpret_cast<const unsigned int*>(p + HID);
        const float z0 = bf2f(zz & 0xffffu), z1 = bf2f(zz >> 16);
        const float f0 = bf2f(ff & 0xffffu), f1 = bf2f(ff >> 16);
        const float o0 = 1.f - f0, o1 = 1.f - f1;
        c0 = f0 * z0 + o0 * c0;  c1 = f1 * z1 + o1 * c1;
        a0 *= o0;                a1 *= o1;
    }
    const int idx = chunk * (BATCH * HID) + b * HID + hp * 2;
    *reinterpret_cast<float2*>(&Aprod[idx]) = make_float2(a0, a1);
    *reinterpret_cast<float2*>(&Cend[idx])  = make_float2(c0, c1);
}

__global__ void __launch_bounds__(256) scan_combine(const float* __restrict__ Aprod,
                                                    const float* __restrict__ Cend,
                                                    const float* __restrict__ hidden,
                                                    float* __restrict__ Cstart,
                                                    float* __restrict__ c_last) {
    const int t = blockIdx.x * 256 + threadIdx.x;  // b*1024 + h
    float c = hidden[t];
#pragma unroll
    for (int j = 0; j < NCHUNK; ++j) {
        const int idx = j * (BATCH * HID) + t;
        Cstart[idx] = c;
        c = Aprod[idx] * c + Cend[idx];
    }
    c_last[t] = c;
}

__global__ void __launch_bounds__(256) scan_phase3(const unsigned short* __restrict__ gates,
                                                   const float* __restrict__ Cstart,
                                                   float* __restrict__ Hout) {
    const int t = blockIdx.x * 256 + threadIdx.x;
    const int hp = t & 511;
    const int b  = (t >> 9) & (BATCH - 1);
    const int chunk = t >> 13;
    const int idx = chunk * (BATCH * HID) + b * HID + hp * 2;
    float2 cs = *reinterpret_cast<const float2*>(&Cstart[idx]);
    float c0 = cs.x, c1 = cs.y;
    const int m0 = chunk * (CHLEN * BATCH) + b;
    const unsigned short* gz = gates + (size_t)m0 * N_TOT + hp * 2;
#pragma unroll 4
    for (int i = 0; i < CHLEN; ++i) {
        const unsigned short* p = gz + (size_t)i * BATCH * N_TOT;
        const unsigned int zz = *reinterpret_cast<const unsigned int*>(p);
        const unsigned int ff = *reinterpret_cast<const unsigned int*>(p + HID);
        const unsigned int oo = *reinterpret_cast<const unsigned int*>(p + 2 * HID);
        const float z0 = bf2f(zz & 0xffffu), z1 = bf2f(zz >> 16);
        const float f0 = bf2f(ff & 0xffffu), f1 = bf2f(ff >> 16);
        const float g0 = bf2f(oo & 0xffffu), g1 = bf2f(oo >> 16);
        c0 = f0 * z0 + (1.f - f0) * c0;
        c1 = f1 * z1 + (1.f - f1) * c1;
        const int m = m0 + i * BATCH;
        *reinterpret_cast<float2*>(&Hout[(size_t)m * HID + hp * 2]) = make_float2(g0 * c0, g1 * c1);
    }
}

// ---------------- launch ----------------
extern "C" void kernel_launch(void* const* d_in, const int* in_sizes, int n_in,
                              void* d_out, int out_size, void* d_ws, size_t ws_size,
                              hipStream_t stream) {
    const float* X      = (const float*)d_in[0];
    const float* hidden = (const float*)d_in[1];
    const float* W      = (const float*)d_in[2];
    const float* bias   = (const float*)d_in[3];
    float* out    = (float*)d_out;
    float* c_last = out + (size_t)M_TOT * HID;   // outputs: H_out then C[-1:]

    char* ws = (char*)d_ws;
    unsigned short* Xb    = (unsigned short*)ws;                                // 64 MiB
    unsigned short* Wb    = (unsigned short*)(ws + (size_t)M_TOT * K_TOT * 2);  // 6 MiB
    unsigned short* gates = Wb + (size_t)N_TOT * K_TOT;                         // 192 MiB bf16
    float* Aprod  = (float*)(gates + (size_t)M_TOT * N_TOT);
    float* Cend   = Aprod + (size_t)NCHUNK * BATCH * HID;
    float* Cstart = Cend  + (size_t)NCHUNK * BATCH * HID;

    cvt_f32_bf16<<<dim3(2048), dim3(256), 0, stream>>>(X, Xb, (int)(M_TOT * K_TOT / 4));
    cvt_f32_bf16<<<dim3(512),  dim3(256), 0, stream>>>(W, Wb, (int)(N_TOT * K_TOT / 4));
    gemm_gates<<<dim3(NWG), dim3(512), 0, stream>>>(Xb, Wb, bias, gates);
    scan_phase1<<<dim3(1024), dim3(256), 0, stream>>>(gates, Aprod, Cend);
    scan_combine<<<dim3(64), dim3(256), 0, stream>>>(Aprod, Cend, hidden, Cstart, c_last);
    scan_phase3<<<dim3(1024), dim3(256), 0, stream>>>(gates, Cstart, out);
}

// Round 6
// 387.480 us; speedup vs baseline: 1.2284x; 1.0907x over previous
//
#include <hip/hip_runtime.h>
#include <hip/hip_bf16.h>
#include <cstdint>
#include <cstddef>

// Problem constants: X[S,B,D], W[3H,D], S=2048 B=16 D=1024 H=1024
#define S_LEN 2048
#define BATCH 16
#define DIM   1024
#define HID   1024
#define M_TOT (S_LEN * BATCH)   // 32768
#define N_TOT (3 * HID)         // 3072
#define K_TOT DIM               // 1024
#define NCHUNK 32
#define CHLEN (S_LEN / NCHUNK)  // 64

// GEMM geometry: 256x256 tile, BK=64, 8 waves (2M x 4N), 16x16x32 MFMA, 8-phase
#define BM 256
#define BN 256
#define BK 64
#define NT (K_TOT / BK)          // 16 K-tiles
#define NITER (NT / 2)           // 8 iters, 2 K-tiles each
#define GRID_M (M_TOT / BM)      // 128
#define GRID_N (N_TOT / BN)      // 12
#define NWG (GRID_M * GRID_N)    // 1536 (divisible by 8)

typedef __bf16 bf16x8 __attribute__((ext_vector_type(8)));
typedef float  f32x4  __attribute__((ext_vector_type(4)));

__device__ __forceinline__ unsigned short f2bf(float f) {
    unsigned int u = __float_as_uint(f);
    u += 0x7FFFu + ((u >> 16) & 1u);   // RNE
    return (unsigned short)(u >> 16);
}
__device__ __forceinline__ float bf2f(unsigned int s) {
    return __uint_as_float(s << 16);
}
__device__ __forceinline__ float fast_sigmoid(float x) { return 1.0f / (1.0f + __expf(-x)); }
__device__ __forceinline__ float fast_tanh(float x)    { return 2.0f / (1.0f + __expf(-2.0f * x)) - 1.0f; }

// ---------------- fp32 -> bf16 conversion (X and W) ----------------
__global__ void __launch_bounds__(256) cvt_f32_bf16(const float* __restrict__ in,
                                                    unsigned short* __restrict__ out, int n4) {
    int i = blockIdx.x * blockDim.x + threadIdx.x;
    const int stride = gridDim.x * blockDim.x;
    for (; i < n4; i += stride) {
        const float4 v = reinterpret_cast<const float4*>(in)[i];
        ushort4 o;
        o.x = f2bf(v.x); o.y = f2bf(v.y); o.z = f2bf(v.z); o.w = f2bf(v.w);
        reinterpret_cast<ushort4*>(out)[i] = o;
    }
}

// ---------------- GEMM: gates = act(X * W^T + b), bf16 out ----------------
// Round-5 proven 8-phase schedule UNCHANGED. New: epilogue restages the C-tile
// through the (now dead) 128 KiB LDS ring so global stores are 512B-contiguous
// per 32-lane group (round-1-proven 1x write pattern vs 2x for 32B pieces).
#define GLOAD_LDS16(gp, lp)                                                         \
    __builtin_amdgcn_global_load_lds((__attribute__((address_space(1))) void*)(gp), \
                                     (__attribute__((address_space(3))) void*)(lp), 16, 0, 0)

__global__ void __launch_bounds__(512, 2)
gemm_gates(const unsigned short* __restrict__ Xb,
           const unsigned short* __restrict__ Wb,
           const float* __restrict__ bias,
           unsigned short* __restrict__ gates) {
    // Single 128 KiB buffer: A-ring [0, 2*BM*BK), B-ring [2*BM*BK, 4*BM*BK).
    // Epilogue reuses it as a [256][256] bf16 C-tile.
    __shared__ __align__(16) unsigned short LDSbuf[4 * BM * BK];
#define AS(s) (LDSbuf + (s) * (BM * BK))
#define BS(s) (LDSbuf + 2 * (BM * BK) + (s) * (BN * BK))

    const int tid  = threadIdx.x;
    const int lane = tid & 63;
    const int wid  = tid >> 6;     // 0..7
    const int wm   = wid >> 2;     // 0..1  (wave out 128x64 at (wm*128, wn*64))
    const int wn   = wid & 3;      // 0..3
    const int lr   = lane & 15;
    const int lc   = (lane >> 4) & 3;

    // XCD-aware bijective swizzle; bn-fastest -> A-panels L2-resident per XCD
    const int swz = (blockIdx.x & 7) * (NWG / 8) + (blockIdx.x >> 3);
    const int bn = swz % GRID_N;
    const int bm = swz / GRID_N;

    // Staging: one issue = 512 thr x 16B = 64 rows x 128B (one quarter-tile).
    // Thread t writes physical 16B-slot p=t&7 of local row rl=t>>3; logical
    // slot g = p ^ (rl&7)  =>  pre-swizzled global column.
    const int srow  = tid >> 3;                                  // 0..63
    const int scolE = (((tid & 7) ^ ((tid >> 3) & 7)) << 3);     // pre-swizzled col
    const unsigned short* gAs = Xb + (size_t)(bm * BM + srow) * K_TOT + scolE;
    const unsigned short* gBs = Wb + (size_t)(bn * BN + srow) * K_TOT + scolE;

#define STAGE_A(T, q) GLOAD_LDS16(gAs + (size_t)(q) * 64 * K_TOT + (T) * BK, \
                                  AS((T) & 1) + (q) * 4096 + tid * 8)
#define STAGE_B(T, q) GLOAD_LDS16(gBs + (size_t)(q) * 64 * K_TOT + (T) * BK, \
                                  BS((T) & 1) + (q) * 4096 + tid * 8)

    // Fragment reads (16x16x32, round-2 proven mapping): row = base+lr,
    // k-elems = kw*32 + lc*8 + 0..7; physical slot = (kw*4+lc) ^ (row&7).
#define LDA(dst, s, mf, kw) do { const int _r = wm * 128 + (mf) * 16 + lr;            \
        dst = *reinterpret_cast<const bf16x8*>(                                        \
            AS(s) + _r * 64 + (((((kw) << 2) | lc) ^ (_r & 7)) << 3)); } while (0)
#define LDB(dst, s, nf, kw) do { const int _r = wn * 64 + (nf) * 16 + lr;             \
        dst = *reinterpret_cast<const bf16x8*>(                                        \
            BS(s) + _r * 64 + (((((kw) << 2) | lc) ^ (_r & 7)) << 3)); } while (0)

#define RD_A(s, MH) do { _Pragma("unroll") for (int mi = 0; mi < 4; ++mi) {           \
        LDA(a[mi][0], s, (MH) * 4 + mi, 0); LDA(a[mi][1], s, (MH) * 4 + mi, 1); } } while (0)
#define RD_B(dst, s, NH) do { _Pragma("unroll") for (int ni = 0; ni < 2; ++ni) {      \
        LDB(dst[ni][0], s, (NH) * 2 + ni, 0); LDB(dst[ni][1], s, (NH) * 2 + ni, 1); } } while (0)

#define MM16(A_, B_, M0, N0) do {                                                     \
    _Pragma("unroll") for (int mi = 0; mi < 4; ++mi)                                  \
    _Pragma("unroll") for (int ni = 0; ni < 2; ++ni) {                                \
        acc[(M0) + mi][(N0) + ni] = __builtin_amdgcn_mfma_f32_16x16x32_bf16(          \
            A_[mi][0], B_[ni][0], acc[(M0) + mi][(N0) + ni], 0, 0, 0);                \
        acc[(M0) + mi][(N0) + ni] = __builtin_amdgcn_mfma_f32_16x16x32_bf16(          \
            A_[mi][1], B_[ni][1], acc[(M0) + mi][(N0) + ni], 0, 0, 0);                \
    } } while (0)

#define BAR __builtin_amdgcn_s_barrier()
#define SP1 __builtin_amdgcn_s_setprio(1)
#define SP0 __builtin_amdgcn_s_setprio(0)

    f32x4 acc[8][4];
#pragma unroll
    for (int m = 0; m < 8; ++m)
#pragma unroll
        for (int n = 0; n < 4; ++n) acc[m][n] = {0.0f, 0.0f, 0.0f, 0.0f};

    bf16x8 a[4][2], b[2][2], b2[2][2];

    // Prologue: tile 0 fully (8), tile 1 partially (6, ordered as steady state)
    STAGE_A(0, 0); STAGE_A(0, 1); STAGE_A(0, 2); STAGE_A(0, 3);
    STAGE_B(0, 0); STAGE_B(0, 1); STAGE_B(0, 2); STAGE_B(0, 3);
    STAGE_A(1, 0); STAGE_A(1, 2);
    STAGE_B(1, 0); STAGE_B(1, 1);
    STAGE_A(1, 1); STAGE_A(1, 3);
    asm volatile("s_waitcnt vmcnt(6)" ::: "memory");   // tile 0 resident
    BAR;

#pragma unroll 1
    for (int j = 0; j < NITER; ++j) {
        const int t0 = 2 * j;          // slot 0
        const int t1 = 2 * j + 1;      // slot 1
        const bool st = (j < NITER - 1);
        // ---- ph1: read A-mh0 + B-nh0 (12); stage B(t1)[q2,q3]; MFMA (0,0) ----
        RD_A(0, 0); RD_B(b, 0, 0);
        STAGE_B(t1, 2); STAGE_B(t1, 3);
        BAR; SP1; MM16(a, b, 0, 0); SP0; BAR;
        // ---- ph2: read B-nh1 (4); stage A(t0+2)[q0,q2]; MFMA (0,1) ----
        RD_B(b2, 0, 1);
        if (st) { STAGE_A(t0 + 2, 0); STAGE_A(t0 + 2, 2); }
        BAR; SP1; MM16(a, b2, 0, 2); SP0; BAR;
        // ---- ph3: read A-mh1 (8); stage B(t0+2)[q0,q1]; MFMA (1,0) ----
        RD_A(0, 1);
        if (st) { STAGE_B(t0 + 2, 0); STAGE_B(t0 + 2, 1); }
        BAR; SP1; MM16(a, b, 4, 0); SP0; BAR;
        // ---- ph4: stage A(t0+2)[q1,q3]; MFMA (1,1); vmcnt -> tile t1 resident ----
        if (st) { STAGE_A(t0 + 2, 1); STAGE_A(t0 + 2, 3); }
        BAR; SP1; MM16(a, b2, 4, 2); SP0;
        if (st) asm volatile("s_waitcnt vmcnt(6)" ::: "memory");
        else    asm volatile("s_waitcnt vmcnt(0)" ::: "memory");
        BAR;
        // ---- ph5: read A-mh0 + B-nh0 of t1 (12); stage B(t0+2)[q2,q3]; MFMA (0,0) ----
        RD_A(1, 0); RD_B(b, 1, 0);
        if (st) { STAGE_B(t0 + 2, 2); STAGE_B(t0 + 2, 3); }
        BAR; SP1; MM16(a, b, 0, 0); SP0; BAR;
        // ---- ph6: read B-nh1 (4); stage A(t1+2)[q0,q2]; MFMA (0,1) ----
        RD_B(b2, 1, 1);
        if (st) { STAGE_A(t1 + 2, 0); STAGE_A(t1 + 2, 2); }
        BAR; SP1; MM16(a, b2, 0, 2); SP0; BAR;
        // ---- ph7: read A-mh1 (8); stage B(t1+2)[q0,q1]; MFMA (1,0) ----
        RD_A(1, 1);
        if (st) { STAGE_B(t1 + 2, 0); STAGE_B(t1 + 2, 1); }
        BAR; SP1; MM16(a, b, 4, 0); SP0; BAR;
        // ---- ph8: stage A(t1+2)[q1,q3]; MFMA (1,1); vmcnt -> tile t0+2 resident ----
        if (st) { STAGE_A(t1 + 2, 1); STAGE_A(t1 + 2, 3); }
        BAR; SP1; MM16(a, b2, 4, 2); SP0;
        if (st) asm volatile("s_waitcnt vmcnt(6)" ::: "memory");
        BAR;
    }
#undef STAGE_A
#undef STAGE_B
#undef LDA
#undef LDB
#undef RD_A
#undef RD_B
#undef MM16
#undef BAR
#undef SP1
#undef SP0

    // ---- Epilogue part 1: bias + activation + f2bf, scatter into LDS C-tile.
    // Ring is dead (final loop BAR: every wave lgkm-drained its reads before its
    // last MFMAs, which precede the barrier). C layout: [256 rows][256 cols] bf16,
    // 512B rows, 16B granules XOR-swizzled by (row&7) to split write banks.
    // acc C/D mapping (proven): col = lane&15 (+nf*16+wn*64), row = (lane>>4)*4+reg.
    const int gate_id = bn >> 2;  // 0:tanh(Z) 1:sig(F) 2:sig(O), uniform per block
    {
        const int rl0 = wm * 128 + ((lane >> 4) << 2);
        const int cl0 = wn * 64 + lr;
#pragma unroll
        for (int nf = 0; nf < 4; ++nf) {
            const int col = cl0 + nf * 16;
            const float bb = bias[bn * BN + col];
#pragma unroll
            for (int mf = 0; mf < 8; ++mf) {
#pragma unroll
                for (int r = 0; r < 4; ++r) {
                    const int row = rl0 + mf * 16 + r;
                    const float y = acc[mf][nf][r] + bb;
                    const float g = (gate_id == 0) ? fast_tanh(y) : fast_sigmoid(y);
                    const int phys = (col >> 3) ^ (row & 7);
                    LDSbuf[row * 256 + (phys << 3) + (col & 7)] = f2bf(g);
                }
            }
        }
    }
    __syncthreads();
    // ---- Epilogue part 2: read back row-linear, store 512B-contiguous per
    // 32-lane group (full HBM sectors -> no write amplification).
    {
        const int gr  = lane & 31;               // 16B granule within row
        const int rsub = lane >> 5;              // 0..1
#pragma unroll
        for (int i = 0; i < 16; ++i) {
            const int rl  = wid * 32 + i * 2 + rsub;
            const int phys = gr ^ (rl & 7);
            const bf16x8 v = *reinterpret_cast<const bf16x8*>(&LDSbuf[rl * 256 + (phys << 3)]);
            *reinterpret_cast<bf16x8*>(&gates[(size_t)(bm * BM + rl) * N_TOT + bn * BN + gr * 8]) = v;
        }
    }
#undef AS
#undef BS
}

// ---------------- chunked linear scan (fo-pool), vec2 over h ----------------
__global__ void __launch_bounds__(256) scan_phase1(const unsigned short* __restrict__ gates,
                                                   float* __restrict__ Aprod,
                                                   float* __restrict__ Cend) {
    const int t = blockIdx.x * 256 + threadIdx.x;  // chunk*8192 + b*512 + hp
    const int hp = t & 511;
    const int b  = (t >> 9) & (BATCH - 1);
    const int chunk = t >> 13;
    float c0 = 0.f, c1 = 0.f, a0 = 1.f, a1 = 1.f;
    const int m0 = chunk * (CHLEN * BATCH) + b;
    const unsigned short* gz = gates + (size_t)m0 * N_TOT + hp * 2;
#pragma unroll 4
    for (int i = 0; i < CHLEN; ++i) {
        const unsigned short* p = gz + (size_t)i * BATCH * N_TOT;
        const unsigned int zz = *reinterpret_cast<const unsigned int*>(p);
        const unsigned int ff = *reinterpret_cast<const unsigned int*>(p + HID);
        const float z0 = bf2f(zz & 0xffffu), z1 = bf2f(zz >> 16);
        const float f0 = bf2f(ff & 0xffffu), f1 = bf2f(ff >> 16);
        const float o0 = 1.f - f0, o1 = 1.f - f1;
        c0 = f0 * z0 + o0 * c0;  c1 = f1 * z1 + o1 * c1;
        a0 *= o0;                a1 *= o1;
    }
    const int idx = chunk * (BATCH * HID) + b * HID + hp * 2;
    *reinterpret_cast<float2*>(&Aprod[idx]) = make_float2(a0, a1);
    *reinterpret_cast<float2*>(&Cend[idx])  = make_float2(c0, c1);
}

__global__ void __launch_bounds__(256) scan_combine(const float* __restrict__ Aprod,
                                                    const float* __restrict__ Cend,
                                                    const float* __restrict__ hidden,
                                                    float* __restrict__ Cstart,
                                                    float* __restrict__ c_last) {
    const int t = blockIdx.x * 256 + threadIdx.x;  // b*1024 + h
    float c = hidden[t];
#pragma unroll
    for (int j = 0; j < NCHUNK; ++j) {
        const int idx = j * (BATCH * HID) + t;
        Cstart[idx] = c;
        c = Aprod[idx] * c + Cend[idx];
    }
    c_last[t] = c;
}

__global__ void __launch_bounds__(256) scan_phase3(const unsigned short* __restrict__ gates,
                                                   const float* __restrict__ Cstart,
                                                   float* __restrict__ Hout) {
    const int t = blockIdx.x * 256 + threadIdx.x;
    const int hp = t & 511;
    const int b  = (t >> 9) & (BATCH - 1);
    const int chunk = t >> 13;
    const int idx = chunk * (BATCH * HID) + b * HID + hp * 2;
    float2 cs = *reinterpret_cast<const float2*>(&Cstart[idx]);
    float c0 = cs.x, c1 = cs.y;
    const int m0 = chunk * (CHLEN * BATCH) + b;
    const unsigned short* gz = gates + (size_t)m0 * N_TOT + hp * 2;
#pragma unroll 4
    for (int i = 0; i < CHLEN; ++i) {
        const unsigned short* p = gz + (size_t)i * BATCH * N_TOT;
        const unsigned int zz = *reinterpret_cast<const unsigned int*>(p);
        const unsigned int ff = *reinterpret_cast<const unsigned int*>(p + HID);
        const unsigned int oo = *reinterpret_cast<const unsigned int*>(p + 2 * HID);
        const float z0 = bf2f(zz & 0xffffu), z1 = bf2f(zz >> 16);
        const float f0 = bf2f(ff & 0xffffu), f1 = bf2f(ff >> 16);
        const float g0 = bf2f(oo & 0xffffu), g1 = bf2f(oo >> 16);
        c0 = f0 * z0 + (1.f - f0) * c0;
        c1 = f1 * z1 + (1.f - f1) * c1;
        const int m = m0 + i * BATCH;
        *reinterpret_cast<float2*>(&Hout[(size_t)m * HID + hp * 2]) = make_float2(g0 * c0, g1 * c1);
    }
}

// ---------------- launch ----------------
extern "C" void kernel_launch(void* const* d_in, const int* in_sizes, int n_in,
                              void* d_out, int out_size, void* d_ws, size_t ws_size,
                              hipStream_t stream) {
    const float* X      = (const float*)d_in[0];
    const float* hidden = (const float*)d_in[1];
    const float* W      = (const float*)d_in[2];
    const float* bias   = (const float*)d_in[3];
    float* out    = (float*)d_out;
    float* c_last = out + (size_t)M_TOT * HID;   // outputs: H_out then C[-1:]

    char* ws = (char*)d_ws;
    unsigned short* Xb    = (unsigned short*)ws;                                // 64 MiB
    unsigned short* Wb    = (unsigned short*)(ws + (size_t)M_TOT * K_TOT * 2);  // 6 MiB
    unsigned short* gates = Wb + (size_t)N_TOT * K_TOT;                         // 192 MiB bf16
    float* Aprod  = (float*)(gates + (size_t)M_TOT * N_TOT);
    float* Cend   = Aprod + (size_t)NCHUNK * BATCH * HID;
    float* Cstart = Cend  + (size_t)NCHUNK * BATCH * HID;

    cvt_f32_bf16<<<dim3(2048), dim3(256), 0, stream>>>(X, Xb, (int)(M_TOT * K_TOT / 4));
    cvt_f32_bf16<<<dim3(512),  dim3(256), 0, stream>>>(W, Wb, (int)(N_TOT * K_TOT / 4));
    gemm_gates<<<dim3(NWG), dim3(512), 0, stream>>>(Xb, Wb, bias, gates);
    scan_phase1<<<dim3(1024), dim3(256), 0, stream>>>(gates, Aprod, Cend);
    scan_combine<<<dim3(64), dim3(256), 0, stream>>>(Aprod, Cend, hidden, Cstart, c_last);
    scan_phase3<<<dim3(1024), dim3(256), 0, stream>>>(gates, Cstart, out);
}